// Round 11
// baseline (682.947 us; speedup 1.0000x reference)
//
#include <hip/hip_runtime.h>

typedef unsigned short u16;
typedef __bf16 bfx8 __attribute__((ext_vector_type(8)));
typedef float f32x4 __attribute__((ext_vector_type(4)));
typedef unsigned short u16x4 __attribute__((ext_vector_type(4)));

#define NN 1024
#define FF 64
#define NSLICE 32
#define KFEAT 11

// ---- workspace layout ----
#define POOL_BYTES (NSLICE * KFEAT * FF * 4)  // 90112
#define MSUM_OFF   POOL_BYTES
#define SLICE0     ((size_t)1 << 20)
#define MB1        (1024u * 1024u)
#define KB128      (131072u)
#define KB256      (262144u)
// bf16 NxN matrices
#define OFF_P    0u
#define OFF_PT   (2u * MB1)
#define OFF_P2   (4u * MB1)
// bf16 [64][1024] transposed narrow operands (15 x 128KB @ 6MB)
#define OFF_XT   (6u * MB1)
#define OFF_Y2T  (6u * MB1 + 1u * KB128)
#define OFF_Y4T  (6u * MB1 + 2u * KB128)
#define OFF_Y6T  (6u * MB1 + 3u * KB128)
#define OFF_Y8T  (6u * MB1 + 4u * KB128)
#define OFF_Y10T (6u * MB1 + 5u * KB128)
#define OFF_Y12T (6u * MB1 + 6u * KB128)
#define OFF_Y14T (6u * MB1 + 7u * KB128)
#define OFF_S1T  (6u * MB1 + 8u * KB128)
#define OFF_S2T  (6u * MB1 + 9u * KB128)
#define OFF_S3T  (6u * MB1 + 10u * KB128)
#define OFF_TQ2  (6u * MB1 + 11u * KB128)
#define OFF_TQ3  (6u * MB1 + 12u * KB128)
#define OFF_TW4  (6u * MB1 + 13u * KB128)
#define OFF_TP6  (6u * MB1 + 14u * KB128)
// f32 [1024][64] narrow results (10 x 256KB @ 8MB)
#define OFF_Y1   (8u * MB1)
#define OFF_Y2   (8u * MB1 + 1u * KB256)
#define OFF_Y4   (8u * MB1 + 2u * KB256)
#define OFF_Y8   (8u * MB1 + 3u * KB256)
#define OFF_PS1  (8u * MB1 + 4u * KB256)
#define OFF_PS2  (8u * MB1 + 5u * KB256)
#define OFF_PS3  (8u * MB1 + 6u * KB256)
#define OFF_QS2  (8u * MB1 + 7u * KB256)
#define OFF_QS3  (8u * MB1 + 8u * KB256)
#define OFF_W4   (8u * MB1 + 9u * KB256)
#define PS_BYTES ((size_t)(11u * MB1))

// async global->LDS, 16B per lane (k_square staging only)
#define GL16(g, l) __builtin_amdgcn_global_load_lds( \
    (const __attribute__((address_space(1))) unsigned int*)(g), \
    (__attribute__((address_space(3))) unsigned int*)(l), 16, 0, 0)

__device__ __forceinline__ u16 f2b(float v) {
  __bf16 h = (__bf16)v;
  return __builtin_bit_cast(u16, h);
}

// ---- P slice: f32 -> bf16 row-major (P) + bf16 transposed (PT) ----
__global__ void k_convP(const float* __restrict__ P, char* ws, int sliceBase) {
  __shared__ float tile[64][65];
  int s = blockIdx.z;
  const float* Ps = P + (size_t)(sliceBase + s) * NN * NN;
  char* base = ws + SLICE0 + (size_t)s * PS_BYTES;
  u16* Pb  = (u16*)(base + OFF_P);
  u16* PbT = (u16*)(base + OFF_PT);
  int r0 = blockIdx.y * 64, c0 = blockIdx.x * 64;
  int tid = threadIdx.x;
  int tc = tid & 15, tr = tid >> 4;
  for (int rr = 0; rr < 64; rr += 16) {
    int r = rr + tr;
    float4 v = *(const float4*)&Ps[(size_t)(r0 + r) * NN + c0 + tc * 4];
    tile[r][tc * 4 + 0] = v.x;
    tile[r][tc * 4 + 1] = v.y;
    tile[r][tc * 4 + 2] = v.z;
    tile[r][tc * 4 + 3] = v.w;
    u16x4 pk = {f2b(v.x), f2b(v.y), f2b(v.z), f2b(v.w)};
    *(u16x4*)&Pb[(size_t)(r0 + r) * NN + c0 + tc * 4] = pk;
  }
  __syncthreads();
  for (int it = 0; it < 4; ++it) {
    int oc = (tid >> 4) + it * 16;
    int ch = tid & 15;
    u16x4 pk = {f2b(tile[ch * 4 + 0][oc]), f2b(tile[ch * 4 + 1][oc]),
                f2b(tile[ch * 4 + 2][oc]), f2b(tile[ch * 4 + 3][oc])};
    *(u16x4*)&PbT[(size_t)(c0 + oc) * NN + r0 + ch * 4] = pk;
  }
}

// ---- X slice: f32 [1024][64] -> bf16 XT [64][1024] ----
__global__ void k_convX(const float* __restrict__ X, char* ws, int sliceBase) {
  __shared__ float tile[64][65];
  int s = blockIdx.z;
  const float* Xs = X + (size_t)(sliceBase + s) * NN * FF;
  u16* XT = (u16*)(ws + SLICE0 + (size_t)s * PS_BYTES + OFF_XT);
  int r0 = blockIdx.x * 64;
  int tx = threadIdx.x & 63, ty = threadIdx.x >> 6;
  for (int rr = 0; rr < 64; rr += 4)
    tile[rr + ty][tx] = Xs[(size_t)(r0 + rr + ty) * FF + tx];
  __syncthreads();
  for (int rr = 0; rr < 64; rr += 4)
    XT[(size_t)(rr + ty) * NN + r0 + tx] = f2b(tile[tx][rr + ty]);
}

__global__ void k_msum(const float* __restrict__ mask, float* msum) {
  int s = blockIdx.x;
  const float* m = mask + (size_t)s * NN;
  int t = threadIdx.x;
  float v = m[t] + m[t + 256] + m[t + 512] + m[t + 768];
  for (int o = 32; o; o >>= 1) v += __shfl_down(v, o);
  __shared__ float ps[4];
  if ((t & 63) == 0) ps[t >> 6] = v;
  __syncthreads();
  if (t == 0) msum[s] = ps[0] + ps[1] + ps[2] + ps[3];
}

// ---- squaring GEMM P2 = P @ P (B given transposed); r6-proven schedule:
// 128x128 tile, BK=32, 4 waves, dbuf, counted vmcnt(4), 32KB LDS,
// chunk-rotation LDS layout (conflict-free, verified 0 conflicts).
__global__ __launch_bounds__(256)
void k_square(char* ws) {
  __shared__ u16 sh[16384];  // 32KB: A bufs @0/4096, B bufs @8192/12288

  unsigned nwg = gridDim.x, wg = blockIdx.x;
  unsigned newid = (wg & 7) * (nwg >> 3) + (wg >> 3);  // slice-per-XCD
  int z = newid >> 6;
  int by = (newid >> 3) & 7, bx = newid & 7;

  char* base = ws + SLICE0 + (size_t)z * PS_BYTES;
  const u16* A  = (const u16*)(base + OFF_P);
  const u16* Bt = (const u16*)(base + OFF_PT);
  u16* C        = (u16*)(base + OFF_P2);

  const int tid = threadIdx.x;
  const int lane = tid & 63, wave = tid >> 6;
  const int wr = wave >> 1, wc = wave & 1;
  const int l16 = lane & 15, lk = lane >> 4;
  const int bm = by * 128, bn = bx * 128;

  const int pc = (((tid & 3) - (tid >> 3)) & 3) << 3;
  const u16* gA = A + (size_t)(bm + (tid >> 2)) * NN + pc;
  const u16* gB = Bt + (size_t)(bn + (tid >> 2)) * NN + pc;
  const int rot = ((lk + (l16 >> 1)) & 3) << 3;

  f32x4 acc[4][4] = {};

#define SQ_STAGE(k0, buf)                                   \
  {                                                         \
    u16* dA = sh + (buf)*4096 + wave * 512;                 \
    u16* dB = sh + 8192 + (buf)*4096 + wave * 512;          \
    GL16(gA + (k0), dA);                                    \
    GL16(gA + 64 * NN + (k0), dA + 2048);                   \
    GL16(gB + (k0), dB);                                    \
    GL16(gB + 64 * NN + (k0), dB + 2048);                   \
  }

#define SQ_COMPUTE(buf)                                                      \
  {                                                                          \
    const u16* bA = sh + (buf)*4096;                                         \
    const u16* bB = sh + 8192 + (buf)*4096;                                  \
    bfx8 af[4], bf[4];                                                       \
    _Pragma("unroll") for (int m = 0; m < 4; ++m)                            \
        af[m] = *(const bfx8*)&bA[(wr * 64 + m * 16 + l16) * 32 + rot];      \
    _Pragma("unroll") for (int n = 0; n < 4; ++n)                            \
        bf[n] = *(const bfx8*)&bB[(wc * 64 + n * 16 + l16) * 32 + rot];      \
    __builtin_amdgcn_s_setprio(1);                                           \
    _Pragma("unroll") for (int m = 0; m < 4; ++m)                            \
        _Pragma("unroll") for (int n = 0; n < 4; ++n)                        \
            acc[m][n] = __builtin_amdgcn_mfma_f32_16x16x32_bf16(             \
                af[m], bf[n], acc[m][n], 0, 0, 0);                           \
    __builtin_amdgcn_s_setprio(0);                                           \
  }

  SQ_STAGE(0, 0);
#pragma unroll 2
  for (int t = 1; t < 32; ++t) {
    SQ_STAGE(t * 32, t & 1);
    asm volatile("s_waitcnt vmcnt(4)" ::: "memory");  // own tile t-1 done
    __builtin_amdgcn_s_barrier();                     // -> globally done
    SQ_COMPUTE((t - 1) & 1);
    __builtin_amdgcn_s_barrier();                     // reads done
  }
  asm volatile("s_waitcnt vmcnt(0)" ::: "memory");
  __builtin_amdgcn_s_barrier();
  SQ_COMPUTE(1);

  // C store (bf16 scalar)
#pragma unroll
  for (int m = 0; m < 4; ++m) {
    int row0 = bm + wr * 64 + m * 16 + lk * 4;
#pragma unroll
    for (int n = 0; n < 4; ++n) {
      int col = bn + wc * 64 + n * 16 + l16;
#pragma unroll
      for (int r = 0; r < 4; ++r)
        C[(size_t)(row0 + r) * NN + col] = f2b(acc[m][n][r]);
    }
  }
}

// ---- fused narrow GEMM, LDS-free: acc_j = A @ B_j with per-lane direct
// global->register fragment loads (A[row][k0+lk*8], Bt[col][k0+lk*8]).
// No barriers, no LDS: reuse is only 2x per byte (wc pair) -> L1/L2 absorbs.
// 64-row M-tiles (16 blocks/slice), 4 waves (2Mx2N), per-wave 32x32/operand.
// Per-slot epilogue flags: d = f32 diff source, pk = pool-|w| feature idx,
// f = f32 out, ta = bf16-T of |w|, tv = bf16-T of v. rawK pools raw slot 0.
struct NA {
  int a, rawK;
  int bt[3], d[3], pk[3], f[3], ta[3], tv[3];
};

template <int NB>
__global__ __launch_bounds__(256)
void k_nar(char* ws, int sliceBase, float* __restrict__ pooled, NA na) {
  unsigned nwg = gridDim.x, wg = blockIdx.x;
  unsigned newid = (wg & 7) * (nwg >> 3) + (wg >> 3);  // slice-per-XCD
  int by = newid & 15;
  int s = newid >> 4;
  char* base = ws + SLICE0 + (size_t)s * PS_BYTES;

  const u16* A = (const u16*)(base + na.a);
  int poolBase = (sliceBase + s) * (KFEAT * FF);

  const int tid = threadIdx.x;
  const int lane = tid & 63, wave = tid >> 6;
  const int wr = wave >> 1, wc = wave & 1;
  const int l16 = lane & 15, lk = lane >> 4;
  const int bm = by * 64;

  // per-lane fragment base pointers (k advances by imm offsets <= 1984B)
  const u16* pA = A + (size_t)(bm + wr * 32 + l16) * NN + lk * 8;
  const u16* pB[NB];
#pragma unroll
  for (int j = 0; j < NB; ++j)
    pB[j] = (const u16*)(base + na.bt[j]) + (size_t)(wc * 32 + l16) * NN + lk * 8;

  f32x4 acc[NB][2][2] = {};

#pragma unroll
  for (int t = 0; t < 32; ++t) {
    const int k0 = t * 32;
    bfx8 a0 = *(const bfx8*)(pA + k0);
    bfx8 a1 = *(const bfx8*)(pA + 16 * NN + k0);
#pragma unroll
    for (int j = 0; j < NB; ++j) {
      bfx8 b0 = *(const bfx8*)(pB[j] + k0);
      bfx8 b1 = *(const bfx8*)(pB[j] + 16 * NN + k0);
      acc[j][0][0] = __builtin_amdgcn_mfma_f32_16x16x32_bf16(a0, b0, acc[j][0][0], 0, 0, 0);
      acc[j][0][1] = __builtin_amdgcn_mfma_f32_16x16x32_bf16(a0, b1, acc[j][0][1], 0, 0, 0);
      acc[j][1][0] = __builtin_amdgcn_mfma_f32_16x16x32_bf16(a1, b0, acc[j][1][0], 0, 0, 0);
      acc[j][1][1] = __builtin_amdgcn_mfma_f32_16x16x32_bf16(a1, b1, acc[j][1][1], 0, 0, 0);
    }
  }

#pragma unroll
  for (int j = 0; j < NB; ++j) {
    const float* D = na.d[j] >= 0 ? (const float*)(base + na.d[j]) : nullptr;
    float* F  = na.f[j]  >= 0 ? (float*)(base + na.f[j])  : nullptr;
    u16* Ta   = na.ta[j] >= 0 ? (u16*)(base + na.ta[j])   : nullptr;
    u16* Tv   = na.tv[j] >= 0 ? (u16*)(base + na.tv[j])   : nullptr;
    bool doRaw = (j == 0) && (na.rawK >= 0);

    float ps[2] = {0.f, 0.f};
    float pr[2] = {0.f, 0.f};

#pragma unroll
    for (int m = 0; m < 2; ++m) {
      int row0 = bm + wr * 32 + m * 16 + lk * 4;
#pragma unroll
      for (int n = 0; n < 2; ++n) {
        int col = wc * 32 + n * 16 + l16;
        float v0 = acc[j][m][n][0], v1 = acc[j][m][n][1];
        float v2 = acc[j][m][n][2], v3 = acc[j][m][n][3];
        float w0 = v0, w1 = v1, w2 = v2, w3 = v3;
        if (D) {
          w0 = v0 - D[(size_t)(row0 + 0) * FF + col];
          w1 = v1 - D[(size_t)(row0 + 1) * FF + col];
          w2 = v2 - D[(size_t)(row0 + 2) * FF + col];
          w3 = v3 - D[(size_t)(row0 + 3) * FF + col];
        }
        float a0 = fabsf(w0), a1 = fabsf(w1), a2 = fabsf(w2), a3 = fabsf(w3);
        if (na.pk[j] >= 0) ps[n] += a0 + a1 + a2 + a3;
        if (doRaw) pr[n] += v0 + v1 + v2 + v3;
        if (F) {
          F[(size_t)(row0 + 0) * FF + col] = v0;
          F[(size_t)(row0 + 1) * FF + col] = v1;
          F[(size_t)(row0 + 2) * FF + col] = v2;
          F[(size_t)(row0 + 3) * FF + col] = v3;
        }
        if (Ta) {
          u16x4 pkk = {f2b(a0), f2b(a1), f2b(a2), f2b(a3)};
          *(u16x4*)&Ta[(size_t)col * NN + row0] = pkk;
        }
        if (Tv) {
          u16x4 pkk = {f2b(v0), f2b(v1), f2b(v2), f2b(v3)};
          *(u16x4*)&Tv[(size_t)col * NN + row0] = pkk;
        }
      }
    }

    if (na.pk[j] >= 0) {
#pragma unroll
      for (int n = 0; n < 2; ++n) {
        float v = ps[n];
        v += __shfl_xor(v, 16);
        v += __shfl_xor(v, 32);
        if (lane < 16)
          atomicAdd(&pooled[poolBase + na.pk[j] * FF + wc * 32 + n * 16 + lane], v);
      }
    }
    if (doRaw) {
#pragma unroll
      for (int n = 0; n < 2; ++n) {
        float v = pr[n];
        v += __shfl_xor(v, 16);
        v += __shfl_xor(v, 32);
        if (lane < 16)
          atomicAdd(&pooled[poolBase + na.rawK * FF + wc * 32 + n * 16 + lane], v);
      }
    }
  }
}

__global__ void k_final(const float* __restrict__ pooled, const float* __restrict__ msum,
                        float* __restrict__ out, int total) {
  int i = blockIdx.x * 256 + threadIdx.x;
  if (i < total) out[i] = pooled[i] / msum[i / (KFEAT * FF)];
}

// helper: one-slot NA
static NA mk1(int a, int rawK, int bt, int d, int pk, int f, int ta, int tv) {
  NA x;
  x.a = a; x.rawK = rawK;
  for (int j = 0; j < 3; ++j) {
    x.bt[j] = -1; x.d[j] = -1; x.pk[j] = -1;
    x.f[j] = -1; x.ta[j] = -1; x.tv[j] = -1;
  }
  x.bt[0] = bt; x.d[0] = d; x.pk[0] = pk; x.f[0] = f; x.ta[0] = ta; x.tv[0] = tv;
  return x;
}
static void setslot(NA& x, int j, int bt, int d, int pk, int f, int ta, int tv) {
  x.bt[j] = bt; x.d[j] = d; x.pk[j] = pk; x.f[j] = f; x.ta[j] = ta; x.tv[j] = tv;
}

extern "C" void kernel_launch(void* const* d_in, const int* in_sizes, int n_in,
                              void* d_out, int out_size, void* d_ws, size_t ws_size,
                              hipStream_t stream) {
  const float* P = (const float*)d_in[0];
  const float* X = (const float*)d_in[1];
  const float* mask = (const float*)d_in[2];
  float* out = (float*)d_out;
  char* ws = (char*)d_ws;
  float* pooled = (float*)ws;
  float* msum = (float*)(ws + MSUM_OFF);

  hipMemsetAsync(pooled, 0, POOL_BYTES, stream);
  k_msum<<<NSLICE, 256, 0, stream>>>(mask, msum);

  int S = 1;
  if (ws_size > SLICE0 + PS_BYTES) S = (int)((ws_size - SLICE0) / PS_BYTES);
  if (S > NSLICE) S = NSLICE;
  if (S < 1) S = 1;

  for (int b0 = 0; b0 < NSLICE; b0 += S) {
    int n = (NSLICE - b0 < S) ? (NSLICE - b0) : S;
    k_convP<<<dim3(16, 16, n), 256, 0, stream>>>(P, ws, b0);
    k_convX<<<dim3(16, 1, n), 256, 0, stream>>>(X, ws, b0);
    // single squaring: P2 = P @ P
    k_square<<<64 * n, 256, 0, stream>>>(ws);

    // ---- Y chain by P2 hops ----
    // c1: Y1 = P X (f32)
    NA c1 = mk1(OFF_P, -1, OFF_XT, -1, -1, OFF_Y1, -1, -1);
    k_nar<1><<<16 * n, 256, 0, stream>>>(ws, b0, pooled, c1);
    // c2: Y2 = P2 X ; s0=|Y2-Y1| pool1 ; Y2 f32 + Y2T
    NA c2 = mk1(OFF_P2, -1, OFF_XT, (int)OFF_Y1, 1, OFF_Y2, -1, OFF_Y2T);
    k_nar<1><<<16 * n, 256, 0, stream>>>(ws, b0, pooled, c2);
    // c3: Y4 = P2 Y2 ; s1=|Y4-Y2| pool2 + S1T ; Y4 f32 + Y4T
    NA c3 = mk1(OFF_P2, -1, OFF_Y2T, (int)OFF_Y2, 2, OFF_Y4, OFF_S1T, OFF_Y4T);
    k_nar<1><<<16 * n, 256, 0, stream>>>(ws, b0, pooled, c3);
    // c4: Y6 = P2 Y4 -> Y6T
    NA c4 = mk1(OFF_P2, -1, OFF_Y4T, -1, -1, -1, -1, OFF_Y6T);
    k_nar<1><<<16 * n, 256, 0, stream>>>(ws, b0, pooled, c4);
    // c5: Y8 = P2 Y6 ; s2=|Y8-Y4| pool3 + S2T ; Y8 f32 + Y8T
    NA c5 = mk1(OFF_P2, -1, OFF_Y6T, (int)OFF_Y4, 3, OFF_Y8, OFF_S2T, OFF_Y8T);
    k_nar<1><<<16 * n, 256, 0, stream>>>(ws, b0, pooled, c5);
    // c6-c8: Y10, Y12, Y14 (T only)
    NA c6 = mk1(OFF_P2, -1, OFF_Y8T, -1, -1, -1, -1, OFF_Y10T);
    k_nar<1><<<16 * n, 256, 0, stream>>>(ws, b0, pooled, c6);
    NA c7 = mk1(OFF_P2, -1, OFF_Y10T, -1, -1, -1, -1, OFF_Y12T);
    k_nar<1><<<16 * n, 256, 0, stream>>>(ws, b0, pooled, c7);
    NA c8 = mk1(OFF_P2, -1, OFF_Y12T, -1, -1, -1, -1, OFF_Y14T);
    k_nar<1><<<16 * n, 256, 0, stream>>>(ws, b0, pooled, c8);
    // c9: Y16 = P2 Y14 ; s3=|Y16-Y8| pool4 + S3T ; F0 raw pool0
    NA c9 = mk1(OFF_P2, 0, OFF_Y14T, (int)OFF_Y8, 4, -1, OFF_S3T, -1);
    k_nar<1><<<16 * n, 256, 0, stream>>>(ws, b0, pooled, c9);

    // ---- second order ----
    // c10 (fused): P * {s1,s2,s3} -> PS1,PS2,PS3
    NA c10 = mk1(OFF_P, -1, OFF_S1T, -1, -1, OFF_PS1, -1, -1);
    setslot(c10, 1, OFF_S2T, -1, -1, OFF_PS2, -1, -1);
    setslot(c10, 2, OFF_S3T, -1, -1, OFF_PS3, -1, -1);
    k_nar<3><<<16 * n, 256, 0, stream>>>(ws, b0, pooled, c10);
    // c11 (fused): P2 * {s1,s2,s3} ; pools 5,6,8 = |P2 s_i - P s_i| ;
    //   keep QS2,QS3 f32 + their T for the P4 hop
    NA c11 = mk1(OFF_P2, -1, OFF_S1T, (int)OFF_PS1, 5, -1, -1, -1);
    setslot(c11, 1, OFF_S2T, (int)OFF_PS2, 6, OFF_QS2, -1, OFF_TQ2);
    setslot(c11, 2, OFF_S3T, (int)OFF_PS3, 8, OFF_QS3, -1, OFF_TQ3);
    k_nar<3><<<16 * n, 256, 0, stream>>>(ws, b0, pooled, c11);
    // c12 (fused): P2 * {TQ2,TQ3} = {P4s2, P4s3} ; pools 7,9 ; W4 f32 + TW4
    NA c12 = mk1(OFF_P2, -1, OFF_TQ2, (int)OFF_QS2, 7, -1, -1, -1);
    setslot(c12, 1, OFF_TQ3, (int)OFF_QS3, 9, OFF_W4, -1, OFF_TW4);
    k_nar<2><<<16 * n, 256, 0, stream>>>(ws, b0, pooled, c12);
    // c13: P6s3 = P2 * TW4 -> TP6
    NA c13 = mk1(OFF_P2, -1, OFF_TW4, -1, -1, -1, -1, OFF_TP6);
    k_nar<1><<<16 * n, 256, 0, stream>>>(ws, b0, pooled, c13);
    // c14: P8s3 = P2 * TP6 ; pool10 = |P8s3 - P4s3|
    NA c14 = mk1(OFF_P2, -1, OFF_TP6, (int)OFF_W4, 10, -1, -1, -1);
    k_nar<1><<<16 * n, 256, 0, stream>>>(ws, b0, pooled, c14);
  }
  int total = NSLICE * KFEAT * FF;
  k_final<<<(total + 255) / 256, 256, 0, stream>>>(pooled, msum, out, total);
}

// Round 12
// 386.913 us; speedup vs baseline: 1.7651x; 1.7651x over previous
//
#include <hip/hip_runtime.h>

typedef unsigned short u16;
typedef __bf16 bfx8 __attribute__((ext_vector_type(8)));
typedef float f32x4 __attribute__((ext_vector_type(4)));
typedef unsigned short u16x4 __attribute__((ext_vector_type(4)));

#define NN 1024
#define FF 64
#define NSLICE 32
#define KFEAT 11

// ---- workspace layout ----
#define POOL_BYTES (NSLICE * KFEAT * FF * 4)  // 90112
#define MSUM_OFF   POOL_BYTES
#define SLICE0     ((size_t)1 << 20)
#define MB1        (1024u * 1024u)
#define KB128      (131072u)
#define KB256      (262144u)
// bf16 NxN matrices
#define OFF_P    0u
#define OFF_PT   (2u * MB1)
#define OFF_P2   (4u * MB1)
// bf16 [64][1024] transposed narrow operands (15 x 128KB @ 6MB)
#define OFF_XT   (6u * MB1)
#define OFF_Y2T  (6u * MB1 + 1u * KB128)
#define OFF_Y4T  (6u * MB1 + 2u * KB128)
#define OFF_Y6T  (6u * MB1 + 3u * KB128)
#define OFF_Y8T  (6u * MB1 + 4u * KB128)
#define OFF_Y10T (6u * MB1 + 5u * KB128)
#define OFF_Y12T (6u * MB1 + 6u * KB128)
#define OFF_Y14T (6u * MB1 + 7u * KB128)
#define OFF_S1T  (6u * MB1 + 8u * KB128)
#define OFF_S2T  (6u * MB1 + 9u * KB128)
#define OFF_S3T  (6u * MB1 + 10u * KB128)
#define OFF_TQ2  (6u * MB1 + 11u * KB128)
#define OFF_TQ3  (6u * MB1 + 12u * KB128)
#define OFF_TW4  (6u * MB1 + 13u * KB128)
#define OFF_TP6  (6u * MB1 + 14u * KB128)
// f32 [1024][64] narrow results (10 x 256KB @ 8MB)
#define OFF_Y1   (8u * MB1)
#define OFF_Y2   (8u * MB1 + 1u * KB256)
#define OFF_Y4   (8u * MB1 + 2u * KB256)
#define OFF_Y8   (8u * MB1 + 3u * KB256)
#define OFF_PS1  (8u * MB1 + 4u * KB256)
#define OFF_PS2  (8u * MB1 + 5u * KB256)
#define OFF_PS3  (8u * MB1 + 6u * KB256)
#define OFF_QS2  (8u * MB1 + 7u * KB256)
#define OFF_QS3  (8u * MB1 + 8u * KB256)
#define OFF_W4   (8u * MB1 + 9u * KB256)
#define PS_BYTES ((size_t)(11u * MB1))

// async global->LDS, 16B per lane; LDS dest = wave-uniform base + lane*16
#define GL16(g, l) __builtin_amdgcn_global_load_lds( \
    (const __attribute__((address_space(1))) unsigned int*)(g), \
    (__attribute__((address_space(3))) unsigned int*)(l), 16, 0, 0)

// Bank-conflict-free chunk rotation (rule #21): linear LDS dest, permuted
// global source chunk, matching permuted read. BK=32 form verified
// (conflicts 9.17M -> 0). BK=64 form (k_nar64) uses 8-chunk rotation:
// stage lane l -> row base+(l>>3), phys chunk l&7, global chunk
// ((l&7)-((l>>3)&7))&7; read phys chunk ((ks*4+lk+(l16&7))&7).

__device__ __forceinline__ u16 f2b(float v) {
  __bf16 h = (__bf16)v;
  return __builtin_bit_cast(u16, h);
}

// ---- P slice: f32 -> bf16 row-major (P) + bf16 transposed (PT) ----
__global__ void k_convP(const float* __restrict__ P, char* ws, int sliceBase) {
  __shared__ float tile[64][65];
  int s = blockIdx.z;
  const float* Ps = P + (size_t)(sliceBase + s) * NN * NN;
  char* base = ws + SLICE0 + (size_t)s * PS_BYTES;
  u16* Pb  = (u16*)(base + OFF_P);
  u16* PbT = (u16*)(base + OFF_PT);
  int r0 = blockIdx.y * 64, c0 = blockIdx.x * 64;
  int tid = threadIdx.x;
  int tc = tid & 15, tr = tid >> 4;
  for (int rr = 0; rr < 64; rr += 16) {
    int r = rr + tr;
    float4 v = *(const float4*)&Ps[(size_t)(r0 + r) * NN + c0 + tc * 4];
    tile[r][tc * 4 + 0] = v.x;
    tile[r][tc * 4 + 1] = v.y;
    tile[r][tc * 4 + 2] = v.z;
    tile[r][tc * 4 + 3] = v.w;
    u16x4 pk = {f2b(v.x), f2b(v.y), f2b(v.z), f2b(v.w)};
    *(u16x4*)&Pb[(size_t)(r0 + r) * NN + c0 + tc * 4] = pk;
  }
  __syncthreads();
  for (int it = 0; it < 4; ++it) {
    int oc = (tid >> 4) + it * 16;
    int ch = tid & 15;
    u16x4 pk = {f2b(tile[ch * 4 + 0][oc]), f2b(tile[ch * 4 + 1][oc]),
                f2b(tile[ch * 4 + 2][oc]), f2b(tile[ch * 4 + 3][oc])};
    *(u16x4*)&PbT[(size_t)(c0 + oc) * NN + r0 + ch * 4] = pk;
  }
}

// ---- X slice: f32 [1024][64] -> bf16 XT [64][1024] ----
__global__ void k_convX(const float* __restrict__ X, char* ws, int sliceBase) {
  __shared__ float tile[64][65];
  int s = blockIdx.z;
  const float* Xs = X + (size_t)(sliceBase + s) * NN * FF;
  u16* XT = (u16*)(ws + SLICE0 + (size_t)s * PS_BYTES + OFF_XT);
  int r0 = blockIdx.x * 64;
  int tx = threadIdx.x & 63, ty = threadIdx.x >> 6;
  for (int rr = 0; rr < 64; rr += 4)
    tile[rr + ty][tx] = Xs[(size_t)(r0 + rr + ty) * FF + tx];
  __syncthreads();
  for (int rr = 0; rr < 64; rr += 4)
    XT[(size_t)(rr + ty) * NN + r0 + tx] = f2b(tile[tx][rr + ty]);
}

__global__ void k_msum(const float* __restrict__ mask, float* msum) {
  int s = blockIdx.x;
  const float* m = mask + (size_t)s * NN;
  int t = threadIdx.x;
  float v = m[t] + m[t + 256] + m[t + 512] + m[t + 768];
  for (int o = 32; o; o >>= 1) v += __shfl_down(v, o);
  __shared__ float ps[4];
  if ((t & 63) == 0) ps[t >> 6] = v;
  __syncthreads();
  if (t == 0) msum[s] = ps[0] + ps[1] + ps[2] + ps[3];
}

// ---- squaring GEMM P2 = P @ P (B given transposed); r6-proven schedule:
// 128x128 tile, BK=32, 4 waves, dbuf, counted vmcnt(4), 32KB LDS.
__global__ __launch_bounds__(256)
void k_square(char* ws) {
  __shared__ u16 sh[16384];  // 32KB: A bufs @0/4096, B bufs @8192/12288

  unsigned nwg = gridDim.x, wg = blockIdx.x;
  unsigned newid = (wg & 7) * (nwg >> 3) + (wg >> 3);  // slice-per-XCD
  int z = newid >> 6;
  int by = (newid >> 3) & 7, bx = newid & 7;

  char* base = ws + SLICE0 + (size_t)z * PS_BYTES;
  const u16* A  = (const u16*)(base + OFF_P);
  const u16* Bt = (const u16*)(base + OFF_PT);
  u16* C        = (u16*)(base + OFF_P2);

  const int tid = threadIdx.x;
  const int lane = tid & 63, wave = tid >> 6;
  const int wr = wave >> 1, wc = wave & 1;
  const int l16 = lane & 15, lk = lane >> 4;
  const int bm = by * 128, bn = bx * 128;

  const int pc = (((tid & 3) - (tid >> 3)) & 3) << 3;
  const u16* gA = A + (size_t)(bm + (tid >> 2)) * NN + pc;
  const u16* gB = Bt + (size_t)(bn + (tid >> 2)) * NN + pc;
  const int rot = ((lk + (l16 >> 1)) & 3) << 3;

  f32x4 acc[4][4] = {};

#define SQ_STAGE(k0, buf)                                   \
  {                                                         \
    u16* dA = sh + (buf)*4096 + wave * 512;                 \
    u16* dB = sh + 8192 + (buf)*4096 + wave * 512;          \
    GL16(gA + (k0), dA);                                    \
    GL16(gA + 64 * NN + (k0), dA + 2048);                   \
    GL16(gB + (k0), dB);                                    \
    GL16(gB + 64 * NN + (k0), dB + 2048);                   \
  }

#define SQ_COMPUTE(buf)                                                      \
  {                                                                          \
    const u16* bA = sh + (buf)*4096;                                         \
    const u16* bB = sh + 8192 + (buf)*4096;                                  \
    bfx8 af[4], bf[4];                                                       \
    _Pragma("unroll") for (int m = 0; m < 4; ++m)                            \
        af[m] = *(const bfx8*)&bA[(wr * 64 + m * 16 + l16) * 32 + rot];      \
    _Pragma("unroll") for (int n = 0; n < 4; ++n)                            \
        bf[n] = *(const bfx8*)&bB[(wc * 64 + n * 16 + l16) * 32 + rot];      \
    __builtin_amdgcn_s_setprio(1);                                           \
    _Pragma("unroll") for (int m = 0; m < 4; ++m)                            \
        _Pragma("unroll") for (int n = 0; n < 4; ++n)                        \
            acc[m][n] = __builtin_amdgcn_mfma_f32_16x16x32_bf16(             \
                af[m], bf[n], acc[m][n], 0, 0, 0);                           \
    __builtin_amdgcn_s_setprio(0);                                           \
  }

  SQ_STAGE(0, 0);
#pragma unroll 2
  for (int t = 1; t < 32; ++t) {
    SQ_STAGE(t * 32, t & 1);
    asm volatile("s_waitcnt vmcnt(4)" ::: "memory");  // own tile t-1 done
    __builtin_amdgcn_s_barrier();                     // -> globally done
    SQ_COMPUTE((t - 1) & 1);
    __builtin_amdgcn_s_barrier();                     // reads done
  }
  asm volatile("s_waitcnt vmcnt(0)" ::: "memory");
  __builtin_amdgcn_s_barrier();
  SQ_COMPUTE(1);

  // C store (bf16 scalar)
#pragma unroll
  for (int m = 0; m < 4; ++m) {
    int row0 = bm + wr * 64 + m * 16 + lk * 4;
#pragma unroll
    for (int n = 0; n < 4; ++n) {
      int col = bn + wc * 64 + n * 16 + l16;
#pragma unroll
      for (int r = 0; r < 4; ++r)
        C[(size_t)(row0 + r) * NN + col] = f2b(acc[m][n][r]);
    }
  }
}

// per-slot epilogue flag pack (shared by k_nar / k_nar64)
struct NA {
  int a, rawK;
  int bt[3], d[3], pk[3], f[3], ta[3], tv[3];
};

// shared epilogue for one operand's acc[2][2]
__device__ __forceinline__ void nar_epilogue(
    char* base, const f32x4 (&acc)[2][2], int bm, int wr, int wc, int l16,
    int lk, int lane, int dof, int pkI, int fo, int tao, int tvo, bool doRaw,
    int rawK, int poolBase, float* __restrict__ pooled) {
  const float* D = dof >= 0 ? (const float*)(base + dof) : nullptr;
  float* F  = fo  >= 0 ? (float*)(base + fo)  : nullptr;
  u16* Ta   = tao >= 0 ? (u16*)(base + tao)   : nullptr;
  u16* Tv   = tvo >= 0 ? (u16*)(base + tvo)   : nullptr;

  float ps[2] = {0.f, 0.f};
  float pr[2] = {0.f, 0.f};

#pragma unroll
  for (int m = 0; m < 2; ++m) {
    int row0 = bm + wr * 32 + m * 16 + lk * 4;
#pragma unroll
    for (int n = 0; n < 2; ++n) {
      int col = wc * 32 + n * 16 + l16;
      float v0 = acc[m][n][0], v1 = acc[m][n][1];
      float v2 = acc[m][n][2], v3 = acc[m][n][3];
      float w0 = v0, w1 = v1, w2 = v2, w3 = v3;
      if (D) {
        w0 = v0 - D[(size_t)(row0 + 0) * FF + col];
        w1 = v1 - D[(size_t)(row0 + 1) * FF + col];
        w2 = v2 - D[(size_t)(row0 + 2) * FF + col];
        w3 = v3 - D[(size_t)(row0 + 3) * FF + col];
      }
      float a0 = fabsf(w0), a1 = fabsf(w1), a2 = fabsf(w2), a3 = fabsf(w3);
      if (pkI >= 0) ps[n] += a0 + a1 + a2 + a3;
      if (doRaw) pr[n] += v0 + v1 + v2 + v3;
      if (F) {
        F[(size_t)(row0 + 0) * FF + col] = v0;
        F[(size_t)(row0 + 1) * FF + col] = v1;
        F[(size_t)(row0 + 2) * FF + col] = v2;
        F[(size_t)(row0 + 3) * FF + col] = v3;
      }
      if (Ta) {
        u16x4 pkk = {f2b(a0), f2b(a1), f2b(a2), f2b(a3)};
        *(u16x4*)&Ta[(size_t)col * NN + row0] = pkk;
      }
      if (Tv) {
        u16x4 pkk = {f2b(v0), f2b(v1), f2b(v2), f2b(v3)};
        *(u16x4*)&Tv[(size_t)col * NN + row0] = pkk;
      }
    }
  }

  if (pkI >= 0) {
#pragma unroll
    for (int n = 0; n < 2; ++n) {
      float v = ps[n];
      v += __shfl_xor(v, 16);
      v += __shfl_xor(v, 32);
      if (lane < 16)
        atomicAdd(&pooled[poolBase + pkI * FF + wc * 32 + n * 16 + lane], v);
    }
  }
  if (doRaw) {
#pragma unroll
    for (int n = 0; n < 2; ++n) {
      float v = pr[n];
      v += __shfl_xor(v, 16);
      v += __shfl_xor(v, 32);
      if (lane < 16)
        atomicAdd(&pooled[poolBase + rawK * FF + wc * 32 + n * 16 + lane], v);
    }
  }
}

// ---- fused narrow GEMM (r10-proven, BK=32): NB B-operands share A staging.
// 64-row M-tiles, 4 waves (2Mx2N), per-wave 32x32/operand, dbuf vmcnt(1+NB).
template <int NB>
__global__ __launch_bounds__(256)
void k_nar(char* ws, int sliceBase, float* __restrict__ pooled, NA na) {
  __shared__ u16 sh[16384];  // 32KB: buf b @ b*8192: A[2048] | B_j[2048]*3
  unsigned nwg = gridDim.x, wg = blockIdx.x;
  unsigned newid = (wg & 7) * (nwg >> 3) + (wg >> 3);  // slice-per-XCD
  int by = newid & 15;
  int s = newid >> 4;
  char* base = ws + SLICE0 + (size_t)s * PS_BYTES;

  const u16* A = (const u16*)(base + na.a);
  int poolBase = (sliceBase + s) * (KFEAT * FF);

  const int tid = threadIdx.x;
  const int lane = tid & 63, wave = tid >> 6;
  const int wr = wave >> 1, wc = wave & 1;
  const int l16 = lane & 15, lk = lane >> 4;
  const int bm = by * 64;

  const int pc = (((tid & 3) - (tid >> 3)) & 3) << 3;
  const u16* gA = A + (size_t)(bm + (tid >> 2)) * NN + pc;
  const u16* gB[NB];
#pragma unroll
  for (int j = 0; j < NB; ++j)
    gB[j] = (const u16*)(base + na.bt[j]) + (size_t)(tid >> 2) * NN + pc;
  const int rot = ((lk + (l16 >> 1)) & 3) << 3;

  f32x4 acc[NB][2][2] = {};

  auto STAGE = [&](int k0, int buf) {
    u16* dA = sh + buf * 8192 + wave * 512;
    GL16(gA + k0, dA);
#pragma unroll
    for (int j = 0; j < NB; ++j) {
      u16* dB = sh + buf * 8192 + 2048 + j * 2048 + wave * 512;
      GL16(gB[j] + k0, dB);
    }
  };
  auto COMPUTE = [&](int buf) {
    const u16* bA = sh + buf * 8192;
    bfx8 af[2];
#pragma unroll
    for (int m = 0; m < 2; ++m)
      af[m] = *(const bfx8*)&bA[(wr * 32 + m * 16 + l16) * 32 + rot];
    __builtin_amdgcn_s_setprio(1);
#pragma unroll
    for (int j = 0; j < NB; ++j) {
      const u16* bB = sh + buf * 8192 + 2048 + j * 2048;
      bfx8 bf[2];
#pragma unroll
      for (int n = 0; n < 2; ++n)
        bf[n] = *(const bfx8*)&bB[(wc * 32 + n * 16 + l16) * 32 + rot];
#pragma unroll
      for (int m = 0; m < 2; ++m)
#pragma unroll
        for (int n = 0; n < 2; ++n)
          acc[j][m][n] = __builtin_amdgcn_mfma_f32_16x16x32_bf16(
              af[m], bf[n], acc[j][m][n], 0, 0, 0);
    }
    __builtin_amdgcn_s_setprio(0);
  };

  STAGE(0, 0);
#pragma unroll 2
  for (int t = 1; t < 32; ++t) {
    STAGE(t * 32, t & 1);
    if constexpr (NB == 2)
      asm volatile("s_waitcnt vmcnt(3)" ::: "memory");
    else
      asm volatile("s_waitcnt vmcnt(4)" ::: "memory");
    __builtin_amdgcn_s_barrier();
    COMPUTE((t - 1) & 1);
    __builtin_amdgcn_s_barrier();
  }
  asm volatile("s_waitcnt vmcnt(0)" ::: "memory");
  __builtin_amdgcn_s_barrier();
  COMPUTE(1);

#pragma unroll
  for (int j = 0; j < NB; ++j) {
    bool doRaw = (j == 0) && (na.rawK >= 0);
    nar_epilogue(base, acc[j], bm, wr, wc, l16, lk, lane, na.d[j], na.pk[j],
                 na.f[j], na.ta[j], na.tv[j], doRaw, na.rawK, poolBase, pooled);
  }
}

// ---- single-B narrow GEMM, BK=64: half the barrier pairs of k_nar<1>.
// 64-row M-tiles, 4 waves (2Mx2N), per-wave 32x32, 16 K-steps, 32KB LDS,
// dbuf vmcnt(4). 8-chunk rotation layout (see top comment).
__global__ __launch_bounds__(256)
void k_nar64(char* ws, int sliceBase, float* __restrict__ pooled, NA na) {
  __shared__ u16 sh[16384];  // 32KB: buf b @ b*8192: A[64][64] | B[64][64]
  unsigned nwg = gridDim.x, wg = blockIdx.x;
  unsigned newid = (wg & 7) * (nwg >> 3) + (wg >> 3);  // slice-per-XCD
  int by = newid & 15;
  int s = newid >> 4;
  char* base = ws + SLICE0 + (size_t)s * PS_BYTES;

  const u16* A  = (const u16*)(base + na.a);
  const u16* Bt = (const u16*)(base + na.bt[0]);
  int poolBase = (sliceBase + s) * (KFEAT * FF);

  const int tid = threadIdx.x;
  const int lane = tid & 63, wave = tid >> 6;
  const int wr = wave >> 1, wc = wave & 1;
  const int l16 = lane & 15, lk = lane >> 4;
  const int bm = by * 64;

  // staging: lane l -> row base+(l>>3), phys chunk l&7,
  // global chunk ((l&7)-((l>>3)&7))&7  (each 8-lane group = one full row)
  const int srow = lane >> 3;
  const int lch = (((lane & 7) - (srow & 7)) & 7) * 8;
  const u16* gA0 = A + (size_t)(bm + wave * 16 + srow) * NN + lch;
  const u16* gA1 = A + (size_t)(bm + wave * 16 + 8 + srow) * NN + lch;
  const u16* gB0 = Bt + (size_t)(wave * 16 + srow) * NN + lch;
  const u16* gB1 = Bt + (size_t)(wave * 16 + 8 + srow) * NN + lch;

  // read rotation: phys chunk = (ks*4 + lk + (l16&7)) & 7
  const int r8 = l16 & 7;

  f32x4 acc[2][2] = {};

#define N64_STAGE(k0, buf)                                  \
  {                                                         \
    u16* dA = sh + (buf)*8192 + wave * 1024;                \
    u16* dB = sh + (buf)*8192 + 4096 + wave * 1024;         \
    GL16(gA0 + (k0), dA);                                   \
    GL16(gA1 + (k0), dA + 512);                             \
    GL16(gB0 + (k0), dB);                                   \
    GL16(gB1 + (k0), dB + 512);                             \
  }

#define N64_COMPUTE(buf)                                                     \
  {                                                                          \
    const u16* bA = sh + (buf)*8192;                                         \
    const u16* bB = sh + (buf)*8192 + 4096;                                  \
    _Pragma("unroll") for (int ks = 0; ks < 2; ++ks) {                       \
      const int ph = ((ks * 4 + lk + r8) & 7) * 8;                           \
      bfx8 af[2], bf[2];                                                     \
      _Pragma("unroll") for (int m = 0; m < 2; ++m)                          \
          af[m] = *(const bfx8*)&bA[(wr * 32 + m * 16 + l16) * 64 + ph];     \
      _Pragma("unroll") for (int n = 0; n < 2; ++n)                          \
          bf[n] = *(const bfx8*)&bB[(wc * 32 + n * 16 + l16) * 64 + ph];     \
      __builtin_amdgcn_s_setprio(1);                                        \
      _Pragma("unroll") for (int m = 0; m < 2; ++m)                          \
          _Pragma("unroll") for (int n = 0; n < 2; ++n)                      \
              acc[m][n] = __builtin_amdgcn_mfma_f32_16x16x32_bf16(           \
                  af[m], bf[n], acc[m][n], 0, 0, 0);                         \
      __builtin_amdgcn_s_setprio(0);                                        \
    }                                                                        \
  }

  N64_STAGE(0, 0);
#pragma unroll 2
  for (int t = 1; t < 16; ++t) {
    N64_STAGE(t * 64, t & 1);
    asm volatile("s_waitcnt vmcnt(4)" ::: "memory");  // own tile t-1 done
    __builtin_amdgcn_s_barrier();
    N64_COMPUTE((t - 1) & 1);
    __builtin_amdgcn_s_barrier();
  }
  asm volatile("s_waitcnt vmcnt(0)" ::: "memory");
  __builtin_amdgcn_s_barrier();
  N64_COMPUTE(1);

  bool doRaw = (na.rawK >= 0);
  nar_epilogue(base, acc, bm, wr, wc, l16, lk, lane, na.d[0], na.pk[0],
               na.f[0], na.ta[0], na.tv[0], doRaw, na.rawK, poolBase, pooled);
}

__global__ void k_final(const float* __restrict__ pooled, const float* __restrict__ msum,
                        float* __restrict__ out, int total) {
  int i = blockIdx.x * 256 + threadIdx.x;
  if (i < total) out[i] = pooled[i] / msum[i / (KFEAT * FF)];
}

// helper: one-slot NA
static NA mk1(int a, int rawK, int bt, int d, int pk, int f, int ta, int tv) {
  NA x;
  x.a = a; x.rawK = rawK;
  for (int j = 0; j < 3; ++j) {
    x.bt[j] = -1; x.d[j] = -1; x.pk[j] = -1;
    x.f[j] = -1; x.ta[j] = -1; x.tv[j] = -1;
  }
  x.bt[0] = bt; x.d[0] = d; x.pk[0] = pk; x.f[0] = f; x.ta[0] = ta; x.tv[0] = tv;
  return x;
}
static void setslot(NA& x, int j, int bt, int d, int pk, int f, int ta, int tv) {
  x.bt[j] = bt; x.d[j] = d; x.pk[j] = pk; x.f[j] = f; x.ta[j] = ta; x.tv[j] = tv;
}

extern "C" void kernel_launch(void* const* d_in, const int* in_sizes, int n_in,
                              void* d_out, int out_size, void* d_ws, size_t ws_size,
                              hipStream_t stream) {
  const float* P = (const float*)d_in[0];
  const float* X = (const float*)d_in[1];
  const float* mask = (const float*)d_in[2];
  float* out = (float*)d_out;
  char* ws = (char*)d_ws;
  float* pooled = (float*)ws;
  float* msum = (float*)(ws + MSUM_OFF);

  hipMemsetAsync(pooled, 0, POOL_BYTES, stream);
  k_msum<<<NSLICE, 256, 0, stream>>>(mask, msum);

  int S = 1;
  if (ws_size > SLICE0 + PS_BYTES) S = (int)((ws_size - SLICE0) / PS_BYTES);
  if (S > NSLICE) S = NSLICE;
  if (S < 1) S = 1;

  for (int b0 = 0; b0 < NSLICE; b0 += S) {
    int n = (NSLICE - b0 < S) ? (NSLICE - b0) : S;
    k_convP<<<dim3(16, 16, n), 256, 0, stream>>>(P, ws, b0);
    k_convX<<<dim3(16, 1, n), 256, 0, stream>>>(X, ws, b0);
    // single squaring: P2 = P @ P
    k_square<<<64 * n, 256, 0, stream>>>(ws);

    // ---- Y chain by P2 hops (BK=64 single-B kernel) ----
    // c1: Y1 = P X (f32)
    NA c1 = mk1(OFF_P, -1, OFF_XT, -1, -1, OFF_Y1, -1, -1);
    k_nar64<<<16 * n, 256, 0, stream>>>(ws, b0, pooled, c1);
    // c2: Y2 = P2 X ; s0=|Y2-Y1| pool1 ; Y2 f32 + Y2T
    NA c2 = mk1(OFF_P2, -1, OFF_XT, (int)OFF_Y1, 1, OFF_Y2, -1, OFF_Y2T);
    k_nar64<<<16 * n, 256, 0, stream>>>(ws, b0, pooled, c2);
    // c3: Y4 = P2 Y2 ; s1=|Y4-Y2| pool2 + S1T ; Y4 f32 + Y4T
    NA c3 = mk1(OFF_P2, -1, OFF_Y2T, (int)OFF_Y2, 2, OFF_Y4, OFF_S1T, OFF_Y4T);
    k_nar64<<<16 * n, 256, 0, stream>>>(ws, b0, pooled, c3);
    // c4: Y6 = P2 Y4 -> Y6T
    NA c4 = mk1(OFF_P2, -1, OFF_Y4T, -1, -1, -1, -1, OFF_Y6T);
    k_nar64<<<16 * n, 256, 0, stream>>>(ws, b0, pooled, c4);
    // c5: Y8 = P2 Y6 ; s2=|Y8-Y4| pool3 + S2T ; Y8 f32 + Y8T
    NA c5 = mk1(OFF_P2, -1, OFF_Y6T, (int)OFF_Y4, 3, OFF_Y8, OFF_S2T, OFF_Y8T);
    k_nar64<<<16 * n, 256, 0, stream>>>(ws, b0, pooled, c5);
    // c6-c8: Y10, Y12, Y14 (T only)
    NA c6 = mk1(OFF_P2, -1, OFF_Y8T, -1, -1, -1, -1, OFF_Y10T);
    k_nar64<<<16 * n, 256, 0, stream>>>(ws, b0, pooled, c6);
    NA c7 = mk1(OFF_P2, -1, OFF_Y10T, -1, -1, -1, -1, OFF_Y12T);
    k_nar64<<<16 * n, 256, 0, stream>>>(ws, b0, pooled, c7);
    NA c8 = mk1(OFF_P2, -1, OFF_Y12T, -1, -1, -1, -1, OFF_Y14T);
    k_nar64<<<16 * n, 256, 0, stream>>>(ws, b0, pooled, c8);
    // c9: Y16 = P2 Y14 ; s3=|Y16-Y8| pool4 + S3T ; F0 raw pool0
    NA c9 = mk1(OFF_P2, 0, OFF_Y14T, (int)OFF_Y8, 4, -1, OFF_S3T, -1);
    k_nar64<<<16 * n, 256, 0, stream>>>(ws, b0, pooled, c9);

    // ---- second order ----
    // c10 (fused): P * {s1,s2,s3} -> PS1,PS2,PS3
    NA c10 = mk1(OFF_P, -1, OFF_S1T, -1, -1, OFF_PS1, -1, -1);
    setslot(c10, 1, OFF_S2T, -1, -1, OFF_PS2, -1, -1);
    setslot(c10, 2, OFF_S3T, -1, -1, OFF_PS3, -1, -1);
    k_nar<3><<<16 * n, 256, 0, stream>>>(ws, b0, pooled, c10);
    // c11 (fused): P2 * {s1,s2,s3} ; pools 5,6,8 = |P2 s_i - P s_i| ;
    //   keep QS2,QS3 f32 + their T for the P4 hop
    NA c11 = mk1(OFF_P2, -1, OFF_S1T, (int)OFF_PS1, 5, -1, -1, -1);
    setslot(c11, 1, OFF_S2T, (int)OFF_PS2, 6, OFF_QS2, -1, OFF_TQ2);
    setslot(c11, 2, OFF_S3T, (int)OFF_PS3, 8, OFF_QS3, -1, OFF_TQ3);
    k_nar<3><<<16 * n, 256, 0, stream>>>(ws, b0, pooled, c11);
    // c12 (fused): P2 * {TQ2,TQ3} = {P4s2, P4s3} ; pools 7,9 ; W4 f32 + TW4
    NA c12 = mk1(OFF_P2, -1, OFF_TQ2, (int)OFF_QS2, 7, -1, -1, -1);
    setslot(c12, 1, OFF_TQ3, (int)OFF_QS3, 9, OFF_W4, -1, OFF_TW4);
    k_nar<2><<<16 * n, 256, 0, stream>>>(ws, b0, pooled, c12);
    // c13: P6s3 = P2 * TW4 -> TP6
    NA c13 = mk1(OFF_P2, -1, OFF_TW4, -1, -1, -1, -1, OFF_TP6);
    k_nar64<<<16 * n, 256, 0, stream>>>(ws, b0, pooled, c13);
    // c14: P8s3 = P2 * TP6 ; pool10 = |P8s3 - P4s3|
    NA c14 = mk1(OFF_P2, -1, OFF_TP6, (int)OFF_W4, 10, -1, -1, -1);
    k_nar64<<<16 * n, 256, 0, stream>>>(ws, b0, pooled, c14);
  }
  int total = NSLICE * KFEAT * FF;
  k_final<<<(total + 255) / 256, 256, 0, stream>>>(pooled, msum, out, total);
}

// Round 13
// 357.032 us; speedup vs baseline: 1.9128x; 1.0837x over previous
//
#include <hip/hip_runtime.h>

typedef unsigned short u16;
typedef __bf16 bfx8 __attribute__((ext_vector_type(8)));
typedef float f32x4 __attribute__((ext_vector_type(4)));
typedef unsigned short u16x4 __attribute__((ext_vector_type(4)));

#define NN 1024
#define FF 64
#define NSLICE 32
#define KFEAT 11

// ---- workspace layout ----
#define POOL_BYTES (NSLICE * KFEAT * FF * 4)  // 90112
#define MSUM_OFF   POOL_BYTES
#define SLICE0     ((size_t)1 << 20)
#define MB1        (1024u * 1024u)
#define KB128      (131072u)
#define KB256      (262144u)
// bf16 NxN matrices
#define OFF_P    0u
#define OFF_PT   (2u * MB1)
#define OFF_P2   (4u * MB1)
// bf16 [64][1024] transposed narrow operands (15 x 128KB @ 6MB)
#define OFF_XT   (6u * MB1)
#define OFF_Y2T  (6u * MB1 + 1u * KB128)
#define OFF_Y4T  (6u * MB1 + 2u * KB128)
#define OFF_Y6T  (6u * MB1 + 3u * KB128)
#define OFF_Y8T  (6u * MB1 + 4u * KB128)
#define OFF_Y10T (6u * MB1 + 5u * KB128)
#define OFF_Y12T (6u * MB1 + 6u * KB128)
#define OFF_Y14T (6u * MB1 + 7u * KB128)
#define OFF_S1T  (6u * MB1 + 8u * KB128)
#define OFF_S2T  (6u * MB1 + 9u * KB128)
#define OFF_S3T  (6u * MB1 + 10u * KB128)
#define OFF_TQ2  (6u * MB1 + 11u * KB128)
#define OFF_TQ3  (6u * MB1 + 12u * KB128)
#define OFF_TW4  (6u * MB1 + 13u * KB128)
#define OFF_TP6  (6u * MB1 + 14u * KB128)
// f32 [1024][64] narrow results
#define OFF_Y2   (8u * MB1)
#define OFF_Y4   (8u * MB1 + 1u * KB256)
#define OFF_Y8   (8u * MB1 + 2u * KB256)
#define OFF_QS2  (8u * MB1 + 3u * KB256)
#define OFF_QS3  (8u * MB1 + 4u * KB256)
#define OFF_W4   (8u * MB1 + 5u * KB256)
#define PS_BYTES ((size_t)(11u * MB1))

// async global->LDS, 16B per lane; LDS dest = wave-uniform base + lane*16
#define GL16(g, l) __builtin_amdgcn_global_load_lds( \
    (const __attribute__((address_space(1))) unsigned int*)(g), \
    (__attribute__((address_space(3))) unsigned int*)(l), 16, 0, 0)

// Bank-conflict-free chunk rotation (rule #21): linear LDS dest, permuted
// global source chunk, matching permuted read. BK=32 form verified
// (conflicts 9.17M -> 0). BK=64 form (k_nar64): 8-chunk rotation,
// verified bit-identical r12.

__device__ __forceinline__ u16 f2b(float v) {
  __bf16 h = (__bf16)v;
  return __builtin_bit_cast(u16, h);
}

// ---- P slice: f32 -> bf16 row-major (P) + bf16 transposed (PT) ----
__global__ void k_convP(const float* __restrict__ P, char* ws, int sliceBase) {
  __shared__ float tile[64][65];
  int s = blockIdx.z;
  const float* Ps = P + (size_t)(sliceBase + s) * NN * NN;
  char* base = ws + SLICE0 + (size_t)s * PS_BYTES;
  u16* Pb  = (u16*)(base + OFF_P);
  u16* PbT = (u16*)(base + OFF_PT);
  int r0 = blockIdx.y * 64, c0 = blockIdx.x * 64;
  int tid = threadIdx.x;
  int tc = tid & 15, tr = tid >> 4;
  for (int rr = 0; rr < 64; rr += 16) {
    int r = rr + tr;
    float4 v = *(const float4*)&Ps[(size_t)(r0 + r) * NN + c0 + tc * 4];
    tile[r][tc * 4 + 0] = v.x;
    tile[r][tc * 4 + 1] = v.y;
    tile[r][tc * 4 + 2] = v.z;
    tile[r][tc * 4 + 3] = v.w;
    u16x4 pk = {f2b(v.x), f2b(v.y), f2b(v.z), f2b(v.w)};
    *(u16x4*)&Pb[(size_t)(r0 + r) * NN + c0 + tc * 4] = pk;
  }
  __syncthreads();
  for (int it = 0; it < 4; ++it) {
    int oc = (tid >> 4) + it * 16;
    int ch = tid & 15;
    u16x4 pk = {f2b(tile[ch * 4 + 0][oc]), f2b(tile[ch * 4 + 1][oc]),
                f2b(tile[ch * 4 + 2][oc]), f2b(tile[ch * 4 + 3][oc])};
    *(u16x4*)&PbT[(size_t)(c0 + oc) * NN + r0 + ch * 4] = pk;
  }
}

// ---- X slice: f32 [1024][64] -> bf16 XT [64][1024] ----
__global__ void k_convX(const float* __restrict__ X, char* ws, int sliceBase) {
  __shared__ float tile[64][65];
  int s = blockIdx.z;
  const float* Xs = X + (size_t)(sliceBase + s) * NN * FF;
  u16* XT = (u16*)(ws + SLICE0 + (size_t)s * PS_BYTES + OFF_XT);
  int r0 = blockIdx.x * 64;
  int tx = threadIdx.x & 63, ty = threadIdx.x >> 6;
  for (int rr = 0; rr < 64; rr += 4)
    tile[rr + ty][tx] = Xs[(size_t)(r0 + rr + ty) * FF + tx];
  __syncthreads();
  for (int rr = 0; rr < 64; rr += 4)
    XT[(size_t)(rr + ty) * NN + r0 + tx] = f2b(tile[tx][rr + ty]);
}

__global__ void k_msum(const float* __restrict__ mask, float* msum) {
  int s = blockIdx.x;
  const float* m = mask + (size_t)s * NN;
  int t = threadIdx.x;
  float v = m[t] + m[t + 256] + m[t + 512] + m[t + 768];
  for (int o = 32; o; o >>= 1) v += __shfl_down(v, o);
  __shared__ float ps[4];
  if ((t & 63) == 0) ps[t >> 6] = v;
  __syncthreads();
  if (t == 0) msum[s] = ps[0] + ps[1] + ps[2] + ps[3];
}

// ---- squaring GEMM P2 = P @ P (B given transposed); r6-proven schedule ----
__global__ __launch_bounds__(256)
void k_square(char* ws) {
  __shared__ u16 sh[16384];  // 32KB

  unsigned nwg = gridDim.x, wg = blockIdx.x;
  unsigned newid = (wg & 7) * (nwg >> 3) + (wg >> 3);  // slice-per-XCD
  int z = newid >> 6;
  int by = (newid >> 3) & 7, bx = newid & 7;

  char* base = ws + SLICE0 + (size_t)z * PS_BYTES;
  const u16* A  = (const u16*)(base + OFF_P);
  const u16* Bt = (const u16*)(base + OFF_PT);
  u16* C        = (u16*)(base + OFF_P2);

  const int tid = threadIdx.x;
  const int lane = tid & 63, wave = tid >> 6;
  const int wr = wave >> 1, wc = wave & 1;
  const int l16 = lane & 15, lk = lane >> 4;
  const int bm = by * 128, bn = bx * 128;

  const int pc = (((tid & 3) - (tid >> 3)) & 3) << 3;
  const u16* gA = A + (size_t)(bm + (tid >> 2)) * NN + pc;
  const u16* gB = Bt + (size_t)(bn + (tid >> 2)) * NN + pc;
  const int rot = ((lk + (l16 >> 1)) & 3) << 3;

  f32x4 acc[4][4] = {};

#define SQ_STAGE(k0, buf)                                   \
  {                                                         \
    u16* dA = sh + (buf)*4096 + wave * 512;                 \
    u16* dB = sh + 8192 + (buf)*4096 + wave * 512;          \
    GL16(gA + (k0), dA);                                    \
    GL16(gA + 64 * NN + (k0), dA + 2048);                   \
    GL16(gB + (k0), dB);                                    \
    GL16(gB + 64 * NN + (k0), dB + 2048);                   \
  }

#define SQ_COMPUTE(buf)                                                      \
  {                                                                          \
    const u16* bA = sh + (buf)*4096;                                         \
    const u16* bB = sh + 8192 + (buf)*4096;                                  \
    bfx8 af[4], bf[4];                                                       \
    _Pragma("unroll") for (int m = 0; m < 4; ++m)                            \
        af[m] = *(const bfx8*)&bA[(wr * 64 + m * 16 + l16) * 32 + rot];      \
    _Pragma("unroll") for (int n = 0; n < 4; ++n)                            \
        bf[n] = *(const bfx8*)&bB[(wc * 64 + n * 16 + l16) * 32 + rot];      \
    __builtin_amdgcn_s_setprio(1);                                           \
    _Pragma("unroll") for (int m = 0; m < 4; ++m)                            \
        _Pragma("unroll") for (int n = 0; n < 4; ++n)                        \
            acc[m][n] = __builtin_amdgcn_mfma_f32_16x16x32_bf16(             \
                af[m], bf[n], acc[m][n], 0, 0, 0);                           \
    __builtin_amdgcn_s_setprio(0);                                           \
  }

  SQ_STAGE(0, 0);
#pragma unroll 2
  for (int t = 1; t < 32; ++t) {
    SQ_STAGE(t * 32, t & 1);
    asm volatile("s_waitcnt vmcnt(4)" ::: "memory");
    __builtin_amdgcn_s_barrier();
    SQ_COMPUTE((t - 1) & 1);
    __builtin_amdgcn_s_barrier();
  }
  asm volatile("s_waitcnt vmcnt(0)" ::: "memory");
  __builtin_amdgcn_s_barrier();
  SQ_COMPUTE(1);

#pragma unroll
  for (int m = 0; m < 4; ++m) {
    int row0 = bm + wr * 64 + m * 16 + lk * 4;
#pragma unroll
    for (int n = 0; n < 4; ++n) {
      int col = bn + wc * 64 + n * 16 + l16;
#pragma unroll
      for (int r = 0; r < 4; ++r)
        C[(size_t)(row0 + r) * NN + col] = f2b(acc[m][n][r]);
    }
  }
}

// per-slot epilogue flag pack
struct NA {
  int a, rawK;
  int bt[3], d[3], pk[3], f[3], ta[3], tv[3];
};

// shared epilogue for one operand's acc[2][2]
__device__ __forceinline__ void nar_epilogue(
    char* base, const f32x4 (&acc)[2][2], int bm, int wr, int wc, int l16,
    int lk, int lane, int dof, int pkI, int fo, int tao, int tvo, bool doRaw,
    int rawK, int poolBase, float* __restrict__ pooled) {
  const float* D = dof >= 0 ? (const float*)(base + dof) : nullptr;
  float* F  = fo  >= 0 ? (float*)(base + fo)  : nullptr;
  u16* Ta   = tao >= 0 ? (u16*)(base + tao)   : nullptr;
  u16* Tv   = tvo >= 0 ? (u16*)(base + tvo)   : nullptr;

  float ps[2] = {0.f, 0.f};
  float pr[2] = {0.f, 0.f};

#pragma unroll
  for (int m = 0; m < 2; ++m) {
    int row0 = bm + wr * 32 + m * 16 + lk * 4;
#pragma unroll
    for (int n = 0; n < 2; ++n) {
      int col = wc * 32 + n * 16 + l16;
      float v0 = acc[m][n][0], v1 = acc[m][n][1];
      float v2 = acc[m][n][2], v3 = acc[m][n][3];
      float w0 = v0, w1 = v1, w2 = v2, w3 = v3;
      if (D) {
        w0 = v0 - D[(size_t)(row0 + 0) * FF + col];
        w1 = v1 - D[(size_t)(row0 + 1) * FF + col];
        w2 = v2 - D[(size_t)(row0 + 2) * FF + col];
        w3 = v3 - D[(size_t)(row0 + 3) * FF + col];
      }
      float a0 = fabsf(w0), a1 = fabsf(w1), a2 = fabsf(w2), a3 = fabsf(w3);
      if (pkI >= 0) ps[n] += a0 + a1 + a2 + a3;
      if (doRaw) pr[n] += v0 + v1 + v2 + v3;
      if (F) {
        F[(size_t)(row0 + 0) * FF + col] = v0;
        F[(size_t)(row0 + 1) * FF + col] = v1;
        F[(size_t)(row0 + 2) * FF + col] = v2;
        F[(size_t)(row0 + 3) * FF + col] = v3;
      }
      if (Ta) {
        u16x4 pkk = {f2b(a0), f2b(a1), f2b(a2), f2b(a3)};
        *(u16x4*)&Ta[(size_t)col * NN + row0] = pkk;
      }
      if (Tv) {
        u16x4 pkk = {f2b(v0), f2b(v1), f2b(v2), f2b(v3)};
        *(u16x4*)&Tv[(size_t)col * NN + row0] = pkk;
      }
    }
  }

  if (pkI >= 0) {
#pragma unroll
    for (int n = 0; n < 2; ++n) {
      float v = ps[n];
      v += __shfl_xor(v, 16);
      v += __shfl_xor(v, 32);
      if (lane < 16)
        atomicAdd(&pooled[poolBase + pkI * FF + wc * 32 + n * 16 + lane], v);
    }
  }
  if (doRaw) {
#pragma unroll
    for (int n = 0; n < 2; ++n) {
      float v = pr[n];
      v += __shfl_xor(v, 16);
      v += __shfl_xor(v, 32);
      if (lane < 16)
        atomicAdd(&pooled[poolBase + rawK * FF + wc * 32 + n * 16 + lane], v);
    }
  }
}

// ---- fused narrow GEMM (r10-proven, BK=32): NB B share A staging ----
template <int NB>
__global__ __launch_bounds__(256)
void k_nar(char* ws, int sliceBase, float* __restrict__ pooled, NA na) {
  __shared__ u16 sh[16384];
  unsigned nwg = gridDim.x, wg = blockIdx.x;
  unsigned newid = (wg & 7) * (nwg >> 3) + (wg >> 3);
  int by = newid & 15;
  int s = newid >> 4;
  char* base = ws + SLICE0 + (size_t)s * PS_BYTES;

  const u16* A = (const u16*)(base + na.a);
  int poolBase = (sliceBase + s) * (KFEAT * FF);

  const int tid = threadIdx.x;
  const int lane = tid & 63, wave = tid >> 6;
  const int wr = wave >> 1, wc = wave & 1;
  const int l16 = lane & 15, lk = lane >> 4;
  const int bm = by * 64;

  const int pc = (((tid & 3) - (tid >> 3)) & 3) << 3;
  const u16* gA = A + (size_t)(bm + (tid >> 2)) * NN + pc;
  const u16* gB[NB];
#pragma unroll
  for (int j = 0; j < NB; ++j)
    gB[j] = (const u16*)(base + na.bt[j]) + (size_t)(tid >> 2) * NN + pc;
  const int rot = ((lk + (l16 >> 1)) & 3) << 3;

  f32x4 acc[NB][2][2] = {};

  auto STAGE = [&](int k0, int buf) {
    u16* dA = sh + buf * 8192 + wave * 512;
    GL16(gA + k0, dA);
#pragma unroll
    for (int j = 0; j < NB; ++j) {
      u16* dB = sh + buf * 8192 + 2048 + j * 2048 + wave * 512;
      GL16(gB[j] + k0, dB);
    }
  };
  auto COMPUTE = [&](int buf) {
    const u16* bA = sh + buf * 8192;
    bfx8 af[2];
#pragma unroll
    for (int m = 0; m < 2; ++m)
      af[m] = *(const bfx8*)&bA[(wr * 32 + m * 16 + l16) * 32 + rot];
    __builtin_amdgcn_s_setprio(1);
#pragma unroll
    for (int j = 0; j < NB; ++j) {
      const u16* bB = sh + buf * 8192 + 2048 + j * 2048;
      bfx8 bf[2];
#pragma unroll
      for (int n = 0; n < 2; ++n)
        bf[n] = *(const bfx8*)&bB[(wc * 32 + n * 16 + l16) * 32 + rot];
#pragma unroll
      for (int m = 0; m < 2; ++m)
#pragma unroll
        for (int n = 0; n < 2; ++n)
          acc[j][m][n] = __builtin_amdgcn_mfma_f32_16x16x32_bf16(
              af[m], bf[n], acc[j][m][n], 0, 0, 0);
    }
    __builtin_amdgcn_s_setprio(0);
  };

  STAGE(0, 0);
#pragma unroll 2
  for (int t = 1; t < 32; ++t) {
    STAGE(t * 32, t & 1);
    if constexpr (NB == 2)
      asm volatile("s_waitcnt vmcnt(3)" ::: "memory");
    else
      asm volatile("s_waitcnt vmcnt(2)" ::: "memory");
    __builtin_amdgcn_s_barrier();
    COMPUTE((t - 1) & 1);
    __builtin_amdgcn_s_barrier();
  }
  asm volatile("s_waitcnt vmcnt(0)" ::: "memory");
  __builtin_amdgcn_s_barrier();
  COMPUTE(1);

#pragma unroll
  for (int j = 0; j < NB; ++j) {
    bool doRaw = (j == 0) && (na.rawK >= 0);
    nar_epilogue(base, acc[j], bm, wr, wc, l16, lk, lane, na.d[j], na.pk[j],
                 na.f[j], na.ta[j], na.tv[j], doRaw, na.rawK, poolBase, pooled);
  }
}

// ---- single-B narrow GEMM, BK=64 (r12-proven, bit-identical) ----
__global__ __launch_bounds__(256)
void k_nar64(char* ws, int sliceBase, float* __restrict__ pooled, NA na) {
  __shared__ u16 sh[16384];
  unsigned nwg = gridDim.x, wg = blockIdx.x;
  unsigned newid = (wg & 7) * (nwg >> 3) + (wg >> 3);
  int by = newid & 15;
  int s = newid >> 4;
  char* base = ws + SLICE0 + (size_t)s * PS_BYTES;

  const u16* A  = (const u16*)(base + na.a);
  const u16* Bt = (const u16*)(base + na.bt[0]);
  int poolBase = (sliceBase + s) * (KFEAT * FF);

  const int tid = threadIdx.x;
  const int lane = tid & 63, wave = tid >> 6;
  const int wr = wave >> 1, wc = wave & 1;
  const int l16 = lane & 15, lk = lane >> 4;
  const int bm = by * 64;

  const int srow = lane >> 3;
  const int lch = (((lane & 7) - (srow & 7)) & 7) * 8;
  const u16* gA0 = A + (size_t)(bm + wave * 16 + srow) * NN + lch;
  const u16* gA1 = A + (size_t)(bm + wave * 16 + 8 + srow) * NN + lch;
  const u16* gB0 = Bt + (size_t)(wave * 16 + srow) * NN + lch;
  const u16* gB1 = Bt + (size_t)(wave * 16 + 8 + srow) * NN + lch;

  const int r8 = l16 & 7;

  f32x4 acc[2][2] = {};

#define N64_STAGE(k0, buf)                                  \
  {                                                         \
    u16* dA = sh + (buf)*8192 + wave * 1024;                \
    u16* dB = sh + (buf)*8192 + 4096 + wave * 1024;         \
    GL16(gA0 + (k0), dA);                                   \
    GL16(gA1 + (k0), dA + 512);                             \
    GL16(gB0 + (k0), dB);                                   \
    GL16(gB1 + (k0), dB + 512);                             \
  }

#define N64_COMPUTE(buf)                                                     \
  {                                                                          \
    const u16* bA = sh + (buf)*8192;                                         \
    const u16* bB = sh + (buf)*8192 + 4096;                                  \
    _Pragma("unroll") for (int ks = 0; ks < 2; ++ks) {                       \
      const int ph = ((ks * 4 + lk + r8) & 7) * 8;                           \
      bfx8 af[2], bf[2];                                                     \
      _Pragma("unroll") for (int m = 0; m < 2; ++m)                          \
          af[m] = *(const bfx8*)&bA[(wr * 32 + m * 16 + l16) * 64 + ph];     \
      _Pragma("unroll") for (int n = 0; n < 2; ++n)                          \
          bf[n] = *(const bfx8*)&bB[(wc * 32 + n * 16 + l16) * 64 + ph];     \
      __builtin_amdgcn_s_setprio(1);                                        \
      _Pragma("unroll") for (int m = 0; m < 2; ++m)                          \
          _Pragma("unroll") for (int n = 0; n < 2; ++n)                      \
              acc[m][n] = __builtin_amdgcn_mfma_f32_16x16x32_bf16(           \
                  af[m], bf[n], acc[m][n], 0, 0, 0);                         \
      __builtin_amdgcn_s_setprio(0);                                        \
    }                                                                        \
  }

  N64_STAGE(0, 0);
#pragma unroll 2
  for (int t = 1; t < 16; ++t) {
    N64_STAGE(t * 64, t & 1);
    asm volatile("s_waitcnt vmcnt(4)" ::: "memory");
    __builtin_amdgcn_s_barrier();
    N64_COMPUTE((t - 1) & 1);
    __builtin_amdgcn_s_barrier();
  }
  asm volatile("s_waitcnt vmcnt(0)" ::: "memory");
  __builtin_amdgcn_s_barrier();
  N64_COMPUTE(1);

  bool doRaw = (na.rawK >= 0);
  nar_epilogue(base, acc, bm, wr, wc, l16, lk, lane, na.d[0], na.pk[0],
               na.f[0], na.ta[0], na.tv[0], doRaw, na.rawK, poolBase, pooled);
}

// ---- merged c1+c2: {Y1=P X, Y2=P2 X} in one kernel (dual-A, shared B=XT).
// s0 = |Y2-Y1| pooled in-register (k=1); Y2 f32 + Y2T out; Y1 never stored.
// BK=32, 3 GL16/tile, 24KB LDS dbuf, vmcnt(3).
__global__ __launch_bounds__(256)
void k_nC12(char* ws, int sliceBase, float* __restrict__ pooled) {
  __shared__ u16 sh[12288];  // buf b @ b*6144: A0 | A1 | B (2048 u16 each)
  unsigned nwg = gridDim.x, wg = blockIdx.x;
  unsigned newid = (wg & 7) * (nwg >> 3) + (wg >> 3);
  int by = newid & 15;
  int s = newid >> 4;
  char* base = ws + SLICE0 + (size_t)s * PS_BYTES;

  const u16* A0 = (const u16*)(base + OFF_P);
  const u16* A1 = (const u16*)(base + OFF_P2);
  const u16* Bt = (const u16*)(base + OFF_XT);
  float* Y2 = (float*)(base + OFF_Y2);
  u16* Y2T = (u16*)(base + OFF_Y2T);
  int poolBase = (sliceBase + s) * (KFEAT * FF);

  const int tid = threadIdx.x;
  const int lane = tid & 63, wave = tid >> 6;
  const int wr = wave >> 1, wc = wave & 1;
  const int l16 = lane & 15, lk = lane >> 4;
  const int bm = by * 64;

  const int pc = (((tid & 3) - (tid >> 3)) & 3) << 3;
  const u16* gA0 = A0 + (size_t)(bm + (tid >> 2)) * NN + pc;
  const u16* gA1 = A1 + (size_t)(bm + (tid >> 2)) * NN + pc;
  const u16* gB  = Bt + (size_t)(tid >> 2) * NN + pc;
  const int rot = ((lk + (l16 >> 1)) & 3) << 3;

  f32x4 acc[2][2][2] = {};  // [ai][m][n]

  auto STAGE = [&](int k0, int buf) {
    GL16(gA0 + k0, sh + buf * 6144 + wave * 512);
    GL16(gA1 + k0, sh + buf * 6144 + 2048 + wave * 512);
    GL16(gB + k0, sh + buf * 6144 + 4096 + wave * 512);
  };
  auto COMPUTE = [&](int buf) {
    const u16* bA0 = sh + buf * 6144;
    const u16* bA1 = sh + buf * 6144 + 2048;
    const u16* bB  = sh + buf * 6144 + 4096;
    bfx8 a0[2], a1[2], bf[2];
#pragma unroll
    for (int m = 0; m < 2; ++m) {
      a0[m] = *(const bfx8*)&bA0[(wr * 32 + m * 16 + l16) * 32 + rot];
      a1[m] = *(const bfx8*)&bA1[(wr * 32 + m * 16 + l16) * 32 + rot];
    }
#pragma unroll
    for (int n = 0; n < 2; ++n)
      bf[n] = *(const bfx8*)&bB[(wc * 32 + n * 16 + l16) * 32 + rot];
    __builtin_amdgcn_s_setprio(1);
#pragma unroll
    for (int m = 0; m < 2; ++m)
#pragma unroll
      for (int n = 0; n < 2; ++n) {
        acc[0][m][n] = __builtin_amdgcn_mfma_f32_16x16x32_bf16(a0[m], bf[n], acc[0][m][n], 0, 0, 0);
        acc[1][m][n] = __builtin_amdgcn_mfma_f32_16x16x32_bf16(a1[m], bf[n], acc[1][m][n], 0, 0, 0);
      }
    __builtin_amdgcn_s_setprio(0);
  };

  STAGE(0, 0);
#pragma unroll 2
  for (int t = 1; t < 32; ++t) {
    STAGE(t * 32, t & 1);
    asm volatile("s_waitcnt vmcnt(3)" ::: "memory");
    __builtin_amdgcn_s_barrier();
    COMPUTE((t - 1) & 1);
    __builtin_amdgcn_s_barrier();
  }
  asm volatile("s_waitcnt vmcnt(0)" ::: "memory");
  __builtin_amdgcn_s_barrier();
  COMPUTE(1);

  float ps[2] = {0.f, 0.f};
#pragma unroll
  for (int m = 0; m < 2; ++m) {
    int row0 = bm + wr * 32 + m * 16 + lk * 4;
#pragma unroll
    for (int n = 0; n < 2; ++n) {
      int col = wc * 32 + n * 16 + l16;
#pragma unroll
      for (int r = 0; r < 4; ++r) {
        float v = acc[1][m][n][r];
        float w = v - acc[0][m][n][r];
        ps[n] += fabsf(w);
        Y2[(size_t)(row0 + r) * FF + col] = v;
      }
      u16x4 pkk = {f2b(acc[1][m][n][0]), f2b(acc[1][m][n][1]),
                   f2b(acc[1][m][n][2]), f2b(acc[1][m][n][3])};
      *(u16x4*)&Y2T[(size_t)col * NN + row0] = pkk;
    }
  }
#pragma unroll
  for (int n = 0; n < 2; ++n) {
    float v = ps[n];
    v += __shfl_xor(v, 16);
    v += __shfl_xor(v, 32);
    if (lane < 16)
      atomicAdd(&pooled[poolBase + 1 * FF + wc * 32 + n * 16 + lane], v);
  }
}

// ---- merged c10+c11: {P s_i, P2 s_i} for i=1..3 in one kernel (2A x 3B).
// pools 5,6,8 = sum|P2 s_i - P s_i| in-register; QS2,QS3 f32 + TQ2,TQ3 out.
// BK=32, 5 GL16/tile, 40KB LDS dbuf, vmcnt(5).
__global__ __launch_bounds__(256)
void k_nC1011(char* ws, int sliceBase, float* __restrict__ pooled) {
  __shared__ u16 sh[20480];  // buf b @ b*10240: A0|A1|B0|B1|B2 (2048 each)
  unsigned nwg = gridDim.x, wg = blockIdx.x;
  unsigned newid = (wg & 7) * (nwg >> 3) + (wg >> 3);
  int by = newid & 15;
  int s = newid >> 4;
  char* base = ws + SLICE0 + (size_t)s * PS_BYTES;

  const u16* A0 = (const u16*)(base + OFF_P);
  const u16* A1 = (const u16*)(base + OFF_P2);
  int poolBase = (sliceBase + s) * (KFEAT * FF);

  const int tid = threadIdx.x;
  const int lane = tid & 63, wave = tid >> 6;
  const int wr = wave >> 1, wc = wave & 1;
  const int l16 = lane & 15, lk = lane >> 4;
  const int bm = by * 64;

  const int pc = (((tid & 3) - (tid >> 3)) & 3) << 3;
  const u16* gA0 = A0 + (size_t)(bm + (tid >> 2)) * NN + pc;
  const u16* gA1 = A1 + (size_t)(bm + (tid >> 2)) * NN + pc;
  const unsigned btOff[3] = {OFF_S1T, OFF_S2T, OFF_S3T};
  const u16* gB[3];
#pragma unroll
  for (int j = 0; j < 3; ++j)
    gB[j] = (const u16*)(base + btOff[j]) + (size_t)(tid >> 2) * NN + pc;
  const int rot = ((lk + (l16 >> 1)) & 3) << 3;

  f32x4 acc[2][3][2][2] = {};  // [ai][j][m][n]

  auto STAGE = [&](int k0, int buf) {
    GL16(gA0 + k0, sh + buf * 10240 + wave * 512);
    GL16(gA1 + k0, sh + buf * 10240 + 2048 + wave * 512);
#pragma unroll
    for (int j = 0; j < 3; ++j)
      GL16(gB[j] + k0, sh + buf * 10240 + 4096 + j * 2048 + wave * 512);
  };
  auto COMPUTE = [&](int buf) {
    const u16* bA0 = sh + buf * 10240;
    const u16* bA1 = sh + buf * 10240 + 2048;
    bfx8 a0[2], a1[2];
#pragma unroll
    for (int m = 0; m < 2; ++m) {
      a0[m] = *(const bfx8*)&bA0[(wr * 32 + m * 16 + l16) * 32 + rot];
      a1[m] = *(const bfx8*)&bA1[(wr * 32 + m * 16 + l16) * 32 + rot];
    }
    __builtin_amdgcn_s_setprio(1);
#pragma unroll
    for (int j = 0; j < 3; ++j) {
      const u16* bB = sh + buf * 10240 + 4096 + j * 2048;
      bfx8 bf[2];
#pragma unroll
      for (int n = 0; n < 2; ++n)
        bf[n] = *(const bfx8*)&bB[(wc * 32 + n * 16 + l16) * 32 + rot];
#pragma unroll
      for (int m = 0; m < 2; ++m)
#pragma unroll
        for (int n = 0; n < 2; ++n) {
          acc[0][j][m][n] = __builtin_amdgcn_mfma_f32_16x16x32_bf16(a0[m], bf[n], acc[0][j][m][n], 0, 0, 0);
          acc[1][j][m][n] = __builtin_amdgcn_mfma_f32_16x16x32_bf16(a1[m], bf[n], acc[1][j][m][n], 0, 0, 0);
        }
    }
    __builtin_amdgcn_s_setprio(0);
  };

  STAGE(0, 0);
#pragma unroll 2
  for (int t = 1; t < 32; ++t) {
    STAGE(t * 32, t & 1);
    asm volatile("s_waitcnt vmcnt(5)" ::: "memory");
    __builtin_amdgcn_s_barrier();
    COMPUTE((t - 1) & 1);
    __builtin_amdgcn_s_barrier();
  }
  asm volatile("s_waitcnt vmcnt(0)" ::: "memory");
  __builtin_amdgcn_s_barrier();
  COMPUTE(1);

  const int pks[3] = {5, 6, 8};
#pragma unroll
  for (int j = 0; j < 3; ++j) {
    float* F = j == 1 ? (float*)(base + OFF_QS2)
                      : (j == 2 ? (float*)(base + OFF_QS3) : nullptr);
    u16* Tv = j == 1 ? (u16*)(base + OFF_TQ2)
                     : (j == 2 ? (u16*)(base + OFF_TQ3) : nullptr);
    float ps[2] = {0.f, 0.f};
#pragma unroll
    for (int m = 0; m < 2; ++m) {
      int row0 = bm + wr * 32 + m * 16 + lk * 4;
#pragma unroll
      for (int n = 0; n < 2; ++n) {
        int col = wc * 32 + n * 16 + l16;
#pragma unroll
        for (int r = 0; r < 4; ++r) {
          float v = acc[1][j][m][n][r];
          float w = v - acc[0][j][m][n][r];
          ps[n] += fabsf(w);
          if (F) F[(size_t)(row0 + r) * FF + col] = v;
        }
        if (Tv) {
          u16x4 pkk = {f2b(acc[1][j][m][n][0]), f2b(acc[1][j][m][n][1]),
                       f2b(acc[1][j][m][n][2]), f2b(acc[1][j][m][n][3])};
          *(u16x4*)&Tv[(size_t)col * NN + row0] = pkk;
        }
      }
    }
#pragma unroll
    for (int n = 0; n < 2; ++n) {
      float v = ps[n];
      v += __shfl_xor(v, 16);
      v += __shfl_xor(v, 32);
      if (lane < 16)
        atomicAdd(&pooled[poolBase + pks[j] * FF + wc * 32 + n * 16 + lane], v);
    }
  }
}

__global__ void k_final(const float* __restrict__ pooled, const float* __restrict__ msum,
                        float* __restrict__ out, int total) {
  int i = blockIdx.x * 256 + threadIdx.x;
  if (i < total) out[i] = pooled[i] / msum[i / (KFEAT * FF)];
}

// helper: one-slot NA
static NA mk1(int a, int rawK, int bt, int d, int pk, int f, int ta, int tv) {
  NA x;
  x.a = a; x.rawK = rawK;
  for (int j = 0; j < 3; ++j) {
    x.bt[j] = -1; x.d[j] = -1; x.pk[j] = -1;
    x.f[j] = -1; x.ta[j] = -1; x.tv[j] = -1;
  }
  x.bt[0] = bt; x.d[0] = d; x.pk[0] = pk; x.f[0] = f; x.ta[0] = ta; x.tv[0] = tv;
  return x;
}
static void setslot(NA& x, int j, int bt, int d, int pk, int f, int ta, int tv) {
  x.bt[j] = bt; x.d[j] = d; x.pk[j] = pk; x.f[j] = f; x.ta[j] = ta; x.tv[j] = tv;
}

extern "C" void kernel_launch(void* const* d_in, const int* in_sizes, int n_in,
                              void* d_out, int out_size, void* d_ws, size_t ws_size,
                              hipStream_t stream) {
  const float* P = (const float*)d_in[0];
  const float* X = (const float*)d_in[1];
  const float* mask = (const float*)d_in[2];
  float* out = (float*)d_out;
  char* ws = (char*)d_ws;
  float* pooled = (float*)ws;
  float* msum = (float*)(ws + MSUM_OFF);

  hipMemsetAsync(pooled, 0, POOL_BYTES, stream);
  k_msum<<<NSLICE, 256, 0, stream>>>(mask, msum);

  int S = 1;
  if (ws_size > SLICE0 + PS_BYTES) S = (int)((ws_size - SLICE0) / PS_BYTES);
  if (S > NSLICE) S = NSLICE;
  if (S < 1) S = 1;

  for (int b0 = 0; b0 < NSLICE; b0 += S) {
    int n = (NSLICE - b0 < S) ? (NSLICE - b0) : S;
    k_convP<<<dim3(16, 16, n), 256, 0, stream>>>(P, ws, b0);
    k_convX<<<dim3(16, 1, n), 256, 0, stream>>>(X, ws, b0);
    // single squaring: P2 = P @ P
    k_square<<<64 * n, 256, 0, stream>>>(ws);

    // merged c1+c2: Y1,Y2 dual-A; pool1 in-register; Y2 f32 + Y2T
    k_nC12<<<16 * n, 256, 0, stream>>>(ws, b0, pooled);
    // c3: Y4 = P2 Y2 ; s1=|Y4-Y2| pool2 + S1T ; Y4 f32 + Y4T
    NA c3 = mk1(OFF_P2, -1, OFF_Y2T, (int)OFF_Y2, 2, OFF_Y4, OFF_S1T, OFF_Y4T);
    k_nar64<<<16 * n, 256, 0, stream>>>(ws, b0, pooled, c3);
    // c4: Y6 = P2 Y4 -> Y6T
    NA c4 = mk1(OFF_P2, -1, OFF_Y4T, -1, -1, -1, -1, OFF_Y6T);
    k_nar64<<<16 * n, 256, 0, stream>>>(ws, b0, pooled, c4);
    // c5: Y8 = P2 Y6 ; s2=|Y8-Y4| pool3 + S2T ; Y8 f32 + Y8T
    NA c5 = mk1(OFF_P2, -1, OFF_Y6T, (int)OFF_Y4, 3, OFF_Y8, OFF_S2T, OFF_Y8T);
    k_nar64<<<16 * n, 256, 0, stream>>>(ws, b0, pooled, c5);
    // c6-c8: Y10, Y12, Y14 (T only)
    NA c6 = mk1(OFF_P2, -1, OFF_Y8T, -1, -1, -1, -1, OFF_Y10T);
    k_nar64<<<16 * n, 256, 0, stream>>>(ws, b0, pooled, c6);
    NA c7 = mk1(OFF_P2, -1, OFF_Y10T, -1, -1, -1, -1, OFF_Y12T);
    k_nar64<<<16 * n, 256, 0, stream>>>(ws, b0, pooled, c7);
    NA c8 = mk1(OFF_P2, -1, OFF_Y12T, -1, -1, -1, -1, OFF_Y14T);
    k_nar64<<<16 * n, 256, 0, stream>>>(ws, b0, pooled, c8);
    // c9: Y16 = P2 Y14 ; s3=|Y16-Y8| pool4 + S3T ; F0 raw pool0
    NA c9 = mk1(OFF_P2, 0, OFF_Y14T, (int)OFF_Y8, 4, -1, OFF_S3T, -1);
    k_nar64<<<16 * n, 256, 0, stream>>>(ws, b0, pooled, c9);

    // merged c10+c11: pools 5,6,8 in-register; QS2,QS3 + TQ2,TQ3
    k_nC1011<<<16 * n, 256, 0, stream>>>(ws, b0, pooled);
    // c12 (fused): P2 * {TQ2,TQ3} = {P4s2, P4s3} ; pools 7,9 ; W4 f32 + TW4
    NA c12 = mk1(OFF_P2, -1, OFF_TQ2, (int)OFF_QS2, 7, -1, -1, -1);
    setslot(c12, 1, OFF_TQ3, (int)OFF_QS3, 9, OFF_W4, -1, OFF_TW4);
    k_nar<2><<<16 * n, 256, 0, stream>>>(ws, b0, pooled, c12);
    // c13: P6s3 = P2 * TW4 -> TP6
    NA c13 = mk1(OFF_P2, -1, OFF_TW4, -1, -1, -1, -1, OFF_TP6);
    k_nar64<<<16 * n, 256, 0, stream>>>(ws, b0, pooled, c13);
    // c14: P8s3 = P2 * TP6 ; pool10 = |P8s3 - P4s3|
    NA c14 = mk1(OFF_P2, -1, OFF_TP6, (int)OFF_W4, 10, -1, -1, -1);
    k_nar64<<<16 * n, 256, 0, stream>>>(ws, b0, pooled, c14);
  }
  int total = NSLICE * KFEAT * FF;
  k_final<<<(total + 255) / 256, 256, 0, stream>>>(pooled, msum, out, total);
}